// Round 1
// baseline (3136.632 us; speedup 1.0000x reference)
//
#include <hip/hip_runtime.h>
#include <cmath>

// ---------------------------------------------------------------------------
// LSTM T=512 B=64 I=512 H=512, fp32 in/out, bf16 MFMA compute.
// Phase A: Xg[t][g][b][h] = X@Wx_g + b_g   (bf16 MFMA GEMM, 128x128 tile)
// Phase B: persistent 64-block scan kernel, weights in registers,
//          h broadcast via global bf16 double buffer + flag barrier.
// ---------------------------------------------------------------------------

typedef __attribute__((ext_vector_type(8)))  short   short8;
typedef __attribute__((ext_vector_type(4)))  short   short4v;
typedef __attribute__((ext_vector_type(4)))  float   f32x4;
typedef __attribute__((ext_vector_type(16))) float   f32x16;
typedef __attribute__((ext_vector_type(2)))  float   f32x2;
typedef __attribute__((ext_vector_type(2)))  unsigned short ushort2v;

#define TSTEPS 512
#define BATCH  64
#define HID    512

__device__ __forceinline__ unsigned short f2bf(float f) {
  unsigned u = __builtin_bit_cast(unsigned, f);
  unsigned r = (u + 0x7FFFu + ((u >> 16) & 1u)) >> 16;
  return (unsigned short)r;
}
__device__ __forceinline__ float bf2f(unsigned short s) {
  unsigned u = ((unsigned)s) << 16;
  return __builtin_bit_cast(float, u);
}
__device__ __forceinline__ void gload_lds16(const void* g, void* l) {
  __builtin_amdgcn_global_load_lds(
      (const __attribute__((address_space(1))) unsigned int*)g,
      (__attribute__((address_space(3))) unsigned int*)l, 16, 0, 0);
}
__device__ __forceinline__ float sigmoidf_(float x) {
  return 1.0f / (1.0f + __expf(-x));
}

// ---------------------------------------------------------------------------
// Prep: transpose+convert the 8 weight matrices [512][512] f32 (k-major)
// into WxT / WhT bf16 [g*512+h][k] (n-major) so GEMM B-tiles and scan
// B-fragments read 8 contiguous k per lane.
// ---------------------------------------------------------------------------
__global__ __launch_bounds__(256) void prep_wT(
    const float* __restrict__ Wax, const float* __restrict__ Wix,
    const float* __restrict__ Wfx, const float* __restrict__ Wox,
    const float* __restrict__ Wah, const float* __restrict__ Wih,
    const float* __restrict__ Wfh, const float* __restrict__ Woh,
    unsigned short* __restrict__ WxT, unsigned short* __restrict__ WhT) {
  __shared__ float tile[32][33];
  int bx = blockIdx.x;              // 8 mats * 256 tiles
  int mat = bx >> 8;
  int t32 = bx & 255;
  int k0 = (t32 & 15) * 32;
  int h0 = (t32 >> 4) * 32;
  const float* S =
      (mat == 0) ? Wax : (mat == 1) ? Wix : (mat == 2) ? Wfx :
      (mat == 3) ? Wox : (mat == 4) ? Wah : (mat == 5) ? Wih :
      (mat == 6) ? Wfh : Woh;
  unsigned short* D = (mat < 4) ? WxT : WhT;
  int g = mat & 3;
  int tx = threadIdx.x & 31, ty = threadIdx.x >> 5;  // ty in [0,8)
#pragma unroll
  for (int r = 0; r < 4; ++r)
    tile[ty + r * 8][tx] = S[(size_t)(k0 + ty + r * 8) * 512 + h0 + tx];
  __syncthreads();
#pragma unroll
  for (int r = 0; r < 4; ++r) {
    int h = h0 + ty + r * 8;
    int k = k0 + tx;
    D[((size_t)(g * 512 + h) << 9) + k] = f2bf(tile[tx][ty + r * 8]);
  }
}

// X f32 [32768][512] -> bf16
__global__ __launch_bounds__(256) void prep_xbf(const float* __restrict__ X,
                                                unsigned short* __restrict__ Xbf) {
  size_t i = (size_t)blockIdx.x * 256 + threadIdx.x;  // 4M threads, 4 elems each
  f32x4 v = *(const f32x4*)(X + i * 4);
  short4v o;
  o[0] = (short)f2bf(v[0]); o[1] = (short)f2bf(v[1]);
  o[2] = (short)f2bf(v[2]); o[3] = (short)f2bf(v[3]);
  *(short4v*)(Xbf + i * 4) = o;
}

__global__ __launch_bounds__(256) void prep_bias(
    const float* __restrict__ ba, const float* __restrict__ bi,
    const float* __restrict__ bf, const float* __restrict__ bo,
    float* __restrict__ biascat) {
  int n = blockIdx.x * 256 + threadIdx.x;  // [0,2048)
  int g = n >> 9, h = n & 511;
  const float* s = (g == 0) ? ba : (g == 1) ? bi : (g == 2) ? bf : bo;
  biascat[n] = s[h];
}

// ---------------------------------------------------------------------------
// Phase A: Xg(bf16)[t][g][b][h] = Xbf @ WxT^T + bias.
// 128x128 tile, BK=64, 4 waves, 16x16x32 bf16 MFMA, global_load_lds(16),
// XOR-swizzled LDS (row stride 128B, slot ^= row&7).
// ---------------------------------------------------------------------------
__global__ __launch_bounds__(256) void gemm_xproj(
    const unsigned short* __restrict__ Xbf,   // [32768][512]
    const unsigned short* __restrict__ WxT,   // [2048][512]
    const float* __restrict__ biascat,        // [2048]
    unsigned short* __restrict__ Xg) {        // [512][4][64][512] bf16
  __shared__ unsigned short Asm[128 * 64];
  __shared__ unsigned short Bsm[128 * 64];
  int bx = blockIdx.x;
  int nt = bx & 15, mt = bx >> 4;
  int m0 = mt * 128, n0 = nt * 128;
  int tid = threadIdx.x;
  int w = tid >> 6, l = tid & 63;
  int wm = (w >> 1) * 64, wn = (w & 1) * 64;
  f32x4 acc[4][4] = {};

  for (int ks = 0; ks < 8; ++ks) {
    int k0 = ks * 64;
    __syncthreads();  // protect LDS from previous iteration's reads
    // stage A and B tiles: 16 instrs each, wave w does 4+4
    int lr = l >> 3;            // sub-row within 8-row group
    int ksl = ((l & 7) ^ lr) * 8;  // pre-swizzled global k-slot
#pragma unroll
    for (int ii = 0; ii < 4; ++ii) {
      int i = w * 4 + ii;
      int r = i * 8 + lr;
      gload_lds16(Xbf + (size_t)(m0 + r) * 512 + k0 + ksl, Asm + i * 512 + l * 8);
    }
#pragma unroll
    for (int ii = 0; ii < 4; ++ii) {
      int i = w * 4 + ii;
      int r = i * 8 + lr;
      gload_lds16(WxT + (size_t)(n0 + r) * 512 + k0 + ksl, Bsm + i * 512 + l * 8);
    }
    __syncthreads();  // drains vmcnt(0): staging complete
#pragma unroll
    for (int kk = 0; kk < 2; ++kk) {
      short8 af[4], bfr[4];
#pragma unroll
      for (int mi = 0; mi < 4; ++mi) {
        int row = wm + mi * 16 + (l & 15);
        int slot = (kk * 4 + (l >> 4)) ^ (row & 7);
        af[mi] = *(const short8*)(Asm + row * 64 + slot * 8);
      }
#pragma unroll
      for (int ni = 0; ni < 4; ++ni) {
        int row = wn + ni * 16 + (l & 15);
        int slot = (kk * 4 + (l >> 4)) ^ (row & 7);
        bfr[ni] = *(const short8*)(Bsm + row * 64 + slot * 8);
      }
#pragma unroll
      for (int mi = 0; mi < 4; ++mi)
#pragma unroll
        for (int ni = 0; ni < 4; ++ni)
          acc[mi][ni] = __builtin_amdgcn_mfma_f32_16x16x32_bf16(
              af[mi], bfr[ni], acc[mi][ni], 0, 0, 0);
    }
  }
  // epilogue: C/D layout col=l&15, row=(l>>4)*4+reg (m89)
#pragma unroll
  for (int mi = 0; mi < 4; ++mi)
#pragma unroll
    for (int ni = 0; ni < 4; ++ni) {
      int col = n0 + wn + ni * 16 + (l & 15);
      float bias = biascat[col];
      int g = col >> 9, h = col & 511;
#pragma unroll
      for (int r = 0; r < 4; ++r) {
        int m = m0 + wm + mi * 16 + (l >> 4) * 4 + r;
        int t = m >> 6, b = m & 63;
        Xg[(((size_t)(t * 4 + g) * 64 + b) << 9) + h] =
            f2bf(acc[mi][ni][r] + bias);
      }
    }
}

// ---------------------------------------------------------------------------
// Phase B: persistent scan. 64 blocks x 256 threads (4 waves).
// Block j owns h-cols [j*8, j*8+8) x 4 gates (N=32). Wave w: mi=w>>1 (batch
// half), kh=w&1 (k half). Weights held in registers for all 512 steps.
// Per-step grid sync via per-block flag stamps (release/acquire, agent).
// ---------------------------------------------------------------------------
__global__ __launch_bounds__(256) void lstm_scan(
    const unsigned short* __restrict__ Xg,   // [512][4][64][512] bf16
    const unsigned short* __restrict__ WhT,  // [2048][512] bf16  ([g*512+h][k])
    unsigned short* __restrict__ hbuf,       // [2][64][512] bf16 (buf0 zeroed)
    int* __restrict__ flags,                 // [64*16] ints, zeroed
    float* __restrict__ out) {               // [512][64][512] f32
  __shared__ unsigned short h_sm[64 * 520];  // row stride 520 shorts = 1040 B
  __shared__ float red_sm[4 * 32 * 33];      // [wave][row][col+pad]
  int j = blockIdx.x;
  int tid = threadIdx.x;
  int w = tid >> 6, l = tid & 63;
  int mi = w >> 1, kh = w & 1;

  // ---- load recurrent weight fragments into registers (once) ----
  // B-frag (32x32x16): col=l&31, k=(l>>5)*8+i
  short8 wf[16];
  {
    int c = l & 31;
    int g = c >> 3;
    int hcol = j * 8 + (c & 7);
    const unsigned short* base = WhT + ((size_t)(g * 512 + hcol) << 9);
#pragma unroll
    for (int kt = 0; kt < 16; ++kt) {
      int k = kh * 256 + kt * 16 + (l >> 5) * 8;
      wf[kt] = *(const short8*)(base + k);
    }
  }

  // elementwise ownership: thread -> batch row eb, col pair (ehc, ehc+1)
  int eb = tid >> 2;
  int ehc = (tid & 3) * 2;
  float sst[2] = {0.f, 0.f};  // cell state, persistent in registers

  for (int t = 0; t < TSTEPS; ++t) {
    // ---- prefetch Xg for this step (hides HBM latency under the barrier)
    float xga[4], xgb[4];
#pragma unroll
    for (int g = 0; g < 4; ++g) {
      unsigned u = *(const unsigned*)(Xg +
          (((size_t)(t * 4 + g) * 64 + eb) << 9) + j * 8 + ehc);
      xga[g] = bf2f((unsigned short)(u & 0xFFFF));
      xgb[g] = bf2f((unsigned short)(u >> 16));
    }
    // ---- wait for all blocks to have published h(t-1)
    if (tid < 64) {
      while (__hip_atomic_load(flags + tid * 16, __ATOMIC_ACQUIRE,
                               __HIP_MEMORY_SCOPE_AGENT) < t) {
      }
    }
    __syncthreads();
    // ---- stage h(t-1): wave w stages rows [w*16, w*16+16)
    const unsigned short* hb = hbuf + (size_t)(t & 1) * 64 * 512;
#pragma unroll
    for (int rr = 0; rr < 16; ++rr) {
      int row = w * 16 + rr;
      gload_lds16(hb + (size_t)row * 512 + l * 8, h_sm + row * 520 + l * 8);
    }
    __syncthreads();  // vmcnt(0) drain: h_sm ready
    // ---- recurrent GEMM quarter: rows mi*32.., k-half kh
    f32x16 acc = {};
#pragma unroll
    for (int kt = 0; kt < 16; ++kt) {
      int row = mi * 32 + (l & 31);
      int k = kh * 256 + kt * 16 + (l >> 5) * 8;
      short8 a = *(const short8*)(h_sm + row * 520 + k);
      acc = __builtin_amdgcn_mfma_f32_32x32x16_bf16(a, wf[kt], acc, 0, 0, 0);
    }
    // ---- publish partials: C/D layout col=l&31, row=(r&3)+8*(r>>2)+4*(l>>5)
    {
      int col = l & 31;
#pragma unroll
      for (int r = 0; r < 16; ++r) {
        int row = (r & 3) + 8 * (r >> 2) + 4 * (l >> 5);
        red_sm[(w * 32 + row) * 33 + col] = acc[r];
      }
    }
    __syncthreads();
    // ---- elementwise gate math for (eb, ehc..ehc+1)
    float hout[2];
    int bmi = eb >> 5, brow = eb & 31;
#pragma unroll
    for (int q = 0; q < 2; ++q) {
      int hc = ehc + q;
      float gv[4];
#pragma unroll
      for (int g = 0; g < 4; ++g) {
        int c = g * 8 + hc;
        gv[g] = red_sm[((bmi * 2 + 0) * 32 + brow) * 33 + c] +
                red_sm[((bmi * 2 + 1) * 32 + brow) * 33 + c] +
                (q ? xgb[g] : xga[g]);
      }
      float a = tanhf(gv[0]);
      float ig = sigmoidf_(gv[1]);
      float fg = sigmoidf_(gv[2]);
      float og = sigmoidf_(gv[3]);
      sst[q] = a * ig + sst[q] * fg;
      hout[q] = tanhf(sst[q]) * og;
    }
    // ---- store outputs
    size_t oidx = ((size_t)t * 64 + eb) * 512 + j * 8 + ehc;
    f32x2 ov; ov[0] = hout[0]; ov[1] = hout[1];
    *(f32x2*)(out + oidx) = ov;
    unsigned short* hn = hbuf + (size_t)((t + 1) & 1) * 64 * 512;
    ushort2v hv; hv[0] = f2bf(hout[0]); hv[1] = f2bf(hout[1]);
    *(ushort2v*)(hn + (size_t)eb * 512 + j * 8 + ehc) = hv;
    __syncthreads();  // all stores drained (vmcnt 0 per wave) before publish
    if (tid == 0)
      __hip_atomic_store(flags + j * 16, t + 1, __ATOMIC_RELEASE,
                         __HIP_MEMORY_SCOPE_AGENT);
  }
}

// ---------------------------------------------------------------------------
// Workspace layout (bytes):
//   0          Xg bf16    134217728
//   134217728  Xbf bf16    33554432
//   167772160  WxT bf16     2097152
//   169869312  WhT bf16     2097152
//   171966464  biascat f32     8192
//   171974656  flags           4096
//   171978752  hbuf          131072
// total ~172.1 MB
// ---------------------------------------------------------------------------
extern "C" void kernel_launch(void* const* d_in, const int* in_sizes, int n_in,
                              void* d_out, int out_size, void* d_ws,
                              size_t ws_size, hipStream_t stream) {
  const float* X   = (const float*)d_in[0];
  const float* Wax = (const float*)d_in[1];
  const float* Wix = (const float*)d_in[2];
  const float* Wfx = (const float*)d_in[3];
  const float* Wox = (const float*)d_in[4];
  const float* Wah = (const float*)d_in[5];
  const float* Wih = (const float*)d_in[6];
  const float* Wfh = (const float*)d_in[7];
  const float* Woh = (const float*)d_in[8];
  const float* ba  = (const float*)d_in[9];
  const float* bi  = (const float*)d_in[10];
  const float* bf  = (const float*)d_in[11];
  const float* bo  = (const float*)d_in[12];

  char* ws = (char*)d_ws;
  unsigned short* Xg   = (unsigned short*)(ws);
  unsigned short* Xbf  = (unsigned short*)(ws + 134217728);
  unsigned short* WxT  = (unsigned short*)(ws + 167772160);
  unsigned short* WhT  = (unsigned short*)(ws + 169869312);
  float*          bcat = (float*)(ws + 171966464);
  int*            flags= (int*)(ws + 171974656);
  unsigned short* hbuf = (unsigned short*)(ws + 171978752);

  // zero flags + hbuf every call (deterministic; graph-capturable)
  hipMemsetAsync(ws + 171974656, 0, 4096 + 131072, stream);

  prep_wT<<<2048, 256, 0, stream>>>(Wax, Wix, Wfx, Wox, Wah, Wih, Wfh, Woh,
                                    WxT, WhT);
  prep_xbf<<<16384, 256, 0, stream>>>(X, Xbf);
  prep_bias<<<8, 256, 0, stream>>>(ba, bi, bf, bo, bcat);
  gemm_xproj<<<4096, 256, 0, stream>>>(Xbf, WxT, bcat, Xg);
  lstm_scan<<<64, 256, 0, stream>>>(Xg, WhT, hbuf, flags, (float*)d_out);
}